// Round 5
// baseline (346.852 us; speedup 1.0000x reference)
//
#include <hip/hip_runtime.h>
#include <cstdint>
#include <math.h>

#define DIMC 192
#define NTOK 256
#define HEADS 6
#define HD 32

typedef __bf16 bf16x8 __attribute__((ext_vector_type(8)));
typedef __bf16 bf16x4 __attribute__((ext_vector_type(4)));
typedef float f32x4 __attribute__((ext_vector_type(4)));

__device__ __forceinline__ void gload_lds16(const __bf16* g, __bf16* l) {
    __builtin_amdgcn_global_load_lds((const __attribute__((address_space(1))) void*)g,
                                     (__attribute__((address_space(3))) void*)l, 16, 0, 0);
}

// ---------------- cast x (fp32) -> xb (bf16) ----------------
__global__ void cast_x(const float* __restrict__ x, __bf16* __restrict__ xb) {
    int i = blockIdx.x * 256 + threadIdx.x;
    float4 a = ((const float4*)x)[i * 2];
    float4 b = ((const float4*)x)[i * 2 + 1];
    bf16x8 o = {(__bf16)a.x, (__bf16)a.y, (__bf16)a.z, (__bf16)a.w,
                (__bf16)b.x, (__bf16)b.y, (__bf16)b.z, (__bf16)b.w};
    ((bf16x8*)xb)[i] = o;
}

// ---------------- transpose+cast weight: wt[n][k] = w[k][n] ----------------
__global__ void transcast(const float* __restrict__ w, __bf16* __restrict__ wt, int K, int N) {
    int i = blockIdx.x * 256 + threadIdx.x;
    int n = i / K, k = i - n * K;
    wt[i] = (__bf16)w[(size_t)k * N + n];
}

// ---------------- biasTb[h][q][k] = (bf16) table[rel[q][k]*6 + h] ----------------
__global__ void biasTb_kernel(const float* __restrict__ table, const int* __restrict__ rel,
                              __bf16* __restrict__ biasTb) {
    int i = blockIdx.x * 256 + threadIdx.x;
    int h = i >> 16;
    int r = i & 65535;
    biasTb[i] = (__bf16)table[rel[r] * 6 + h];
}

// ---------------- cm[h][w][q][k] = bf16(biasTb[h][q][k] + mask[w][q][k]) ----------------
// grid (384, 32): x = w*6+h (same-w adjacent -> mask L2 reuse), y = 8-row q slice
__global__ void cm_kernel(const __bf16* __restrict__ biasTb, const float* __restrict__ mask,
                          __bf16* __restrict__ cm) {
    int wh = blockIdx.x;
    int w = wh / 6, h = wh - w * 6;
    int q = blockIdx.y * 8 + (threadIdx.x >> 5);
    int k0 = (threadIdx.x & 31) * 8;
    bf16x8 bv = *(const bf16x8*)(biasTb + (size_t)h * 65536 + q * 256 + k0);
    const float* mp = mask + (size_t)w * 65536 + q * 256 + k0;
    float4 ma = *(const float4*)mp;
    float4 mb = *(const float4*)(mp + 4);
    bf16x8 o = {(__bf16)((float)bv[0] + ma.x), (__bf16)((float)bv[1] + ma.y),
                (__bf16)((float)bv[2] + ma.z), (__bf16)((float)bv[3] + ma.w),
                (__bf16)((float)bv[4] + mb.x), (__bf16)((float)bv[5] + mb.y),
                (__bf16)((float)bv[6] + mb.z), (__bf16)((float)bv[7] + mb.w)};
    *(bf16x8*)(cm + ((size_t)(h * 64 + w)) * 65536 + q * 256 + k0) = o;
}

// ---------------- QKV GEMM via MFMA (C^T orientation, direct vector stores) ----------------
__launch_bounds__(256, 3)
__global__ void qkv_mfma(const __bf16* __restrict__ A, const __bf16* __restrict__ Wt,
                         const float* __restrict__ bias,
                         __bf16* __restrict__ qo, __bf16* __restrict__ ko, __bf16* __restrict__ vo) {
    __shared__ __bf16 As[256 * 64];    // 32KB
    __shared__ __bf16 Bs[96 * 64];     // 12KB
    const int t = threadIdx.x;
    const int wv = t >> 6, lane = t & 63;
    const int l16 = lane & 15, quad = lane >> 4;
    const int bx = blockIdx.x;
    const int m0 = blockIdx.y * 256;
    const int j0 = bx * 96;

    f32x4 acc[4][6];
    #pragma unroll
    for (int mt = 0; mt < 4; ++mt)
        #pragma unroll
        for (int nt = 0; nt < 6; ++nt)
            acc[mt][nt] = (f32x4){0.f, 0.f, 0.f, 0.f};

    for (int kit = 0; kit < 3; ++kit) {
        const int k0 = kit * 64;
        #pragma unroll
        for (int gi = 0; gi < 8; ++gi) {
            int g = wv * 8 + gi;
            int cid = g * 64 + lane;
            int row = cid >> 3, kcs = cid & 7;
            int kcg = kcs ^ (row & 7);
            gload_lds16(A + (size_t)(m0 + row) * DIMC + k0 + kcg * 8, As + g * 512);
        }
        #pragma unroll
        for (int gi = 0; gi < 3; ++gi) {
            int g = wv * 3 + gi;
            int cid = g * 64 + lane;
            int n = cid >> 3, kcs = cid & 7;
            int kcg = kcs ^ (n & 7);
            gload_lds16(Wt + (size_t)(j0 + n) * DIMC + k0 + kcg * 8, Bs + g * 512);
        }
        __syncthreads();
        #pragma unroll
        for (int kk = 0; kk < 2; ++kk) {
            bf16x8 af[4], bfr[6];
            #pragma unroll
            for (int mt = 0; mt < 4; ++mt) {
                int row = wv * 64 + mt * 16 + l16;
                int ch = (kk * 4 + quad) ^ (row & 7);
                af[mt] = *(const bf16x8*)(As + row * 64 + ch * 8);
            }
            #pragma unroll
            for (int nt = 0; nt < 6; ++nt) {
                int n = nt * 16 + l16;
                int ch = (kk * 4 + quad) ^ (n & 7);
                bfr[nt] = *(const bf16x8*)(Bs + n * 64 + ch * 8);
            }
            #pragma unroll
            for (int mt = 0; mt < 4; ++mt)
                #pragma unroll
                for (int nt = 0; nt < 6; ++nt)   // C^T: row = W-col, col = token
                    acc[mt][nt] = __builtin_amdgcn_mfma_f32_16x16x32_bf16(bfr[nt], af[mt], acc[mt][nt], 0, 0, 0);
        }
        __syncthreads();
    }

    const int which = bx >> 1;                  // 0=q, 1=k, 2=v
    __bf16* outp = which == 0 ? qo : (which == 1 ? ko : vo);
    const float sc = which == 0 ? 0.17677669529663687f : 1.0f;
    const int cloc = (bx & 1) * 96;
    #pragma unroll
    for (int nt = 0; nt < 6; ++nt) {
        int colL = cloc + nt * 16 + quad * 4;   // local col in [0,192), 4-aligned
        int h = colL >> 5, d0 = colL & 31;
        f32x4 bv = *(const f32x4*)(bias + j0 + nt * 16 + quad * 4);
        #pragma unroll
        for (int mt = 0; mt < 4; ++mt) {
            int token = m0 + wv * 64 + mt * 16 + l16;
            int b = token >> 8, n = token & 255;
            bf16x4 ov;
            #pragma unroll
            for (int r = 0; r < 4; ++r)
                ov[r] = (__bf16)((acc[mt][nt][r] + bv[r]) * sc);
            *(bf16x4*)(outp + (((size_t)b * HEADS + h) * NTOK + n) * HD + d0) = ov;
        }
    }
}

// ---------------- MFMA attention: combined bf16 bias+mask, pipelined chunks ----------------
__launch_bounds__(256, 3)
__global__ void attn_mfma(const __bf16* __restrict__ qg, const __bf16* __restrict__ kg,
                          const __bf16* __restrict__ vg, const __bf16* __restrict__ cm,
                          __bf16* __restrict__ aout) {
    __shared__ __bf16 Ks[NTOK][40];
    __shared__ __bf16 VTs[HD][264];
    __shared__ __bf16 Ps[4][16][40];
    __shared__ float  Sums[4][64];
    const int g = blockIdx.x;                   // = (h*64 + w)*4 + rep
    const int h = g >> 8;
    const int w = (g >> 2) & 63;
    const int rep = g & 3;
    const int b = rep * 64 + w;
    const int bh = b * HEADS + h;
    const int t = threadIdx.x;
    const size_t base = (size_t)bh * (NTOK * HD);

    #pragma unroll
    for (int it = 0; it < 4; ++it) {            // K: [key][dim]
        int c = t + 256 * it;
        int row = c >> 2, off = c & 3;
        *(uint4*)(&Ks[row][off * 8]) = *(const uint4*)(kg + base + row * HD + off * 8);
    }
    #pragma unroll
    for (int it = 0; it < 4; ++it) {            // V: transpose [n][d] -> [d][n]
        int d0 = it * 8;
        bf16x8 vv = *(const bf16x8*)(vg + base + t * HD + d0);
        #pragma unroll
        for (int j = 0; j < 8; ++j)
            VTs[d0 + j][t] = vv[j];
    }
    __syncthreads();

    const int wv = t >> 6, lane = t & 63;
    const int l16 = lane & 15, quad = lane >> 4;
    const int q0 = wv * 64;

    bf16x8 qf[4];
    #pragma unroll
    for (int qt = 0; qt < 4; ++qt)
        qf[qt] = *(const bf16x8*)(qg + base + (size_t)(q0 + qt * 16 + l16) * HD + quad * 8);

    f32x4 o[4][2];
    #pragma unroll
    for (int qt = 0; qt < 4; ++qt)
        #pragma unroll
        for (int dt = 0; dt < 2; ++dt)
            o[qt][dt] = (f32x4){0.f, 0.f, 0.f, 0.f};
    float rsum[4] = {};

    // S^T tile: row = key = quad*4+r, col = qrow = l16
    const __bf16* cmb = cm + (size_t)(h * 64 + w) * 65536 + (size_t)(q0 + l16) * 256 + quad * 4;

    // prologue: chunk-0 operands
    bf16x4 cmv[4][2];
    bf16x8 kfc[2], vfc[2];
    #pragma unroll
    for (int qt = 0; qt < 4; ++qt)
        #pragma unroll
        for (int kt = 0; kt < 2; ++kt)
            cmv[qt][kt] = *(const bf16x4*)(cmb + qt * 4096 + kt * 16);
    #pragma unroll
    for (int kt = 0; kt < 2; ++kt)
        kfc[kt] = *(const bf16x8*)(&Ks[kt * 16 + l16][quad * 8]);
    #pragma unroll
    for (int dt = 0; dt < 2; ++dt)
        vfc[dt] = *(const bf16x8*)(&VTs[dt * 16 + l16][quad * 8]);

    #pragma unroll
    for (int c = 0; c < 8; ++c) {
        const int kbn = ((c + 1) & 7) * 32;     // next chunk (wraps, values unused at c=7)
        bf16x4 cmn[4][2];
        bf16x8 kfn[2], vfn[2];
        #pragma unroll
        for (int qt = 0; qt < 4; ++qt)
            #pragma unroll
            for (int kt = 0; kt < 2; ++kt)
                cmn[qt][kt] = *(const bf16x4*)(cmb + qt * 4096 + kbn + kt * 16);
        #pragma unroll
        for (int kt = 0; kt < 2; ++kt)
            kfn[kt] = *(const bf16x8*)(&Ks[kbn + kt * 16 + l16][quad * 8]);
        #pragma unroll
        for (int dt = 0; dt < 2; ++dt)
            vfn[dt] = *(const bf16x8*)(&VTs[dt * 16 + l16][kbn + quad * 8]);

        #pragma unroll
        for (int qt = 0; qt < 4; ++qt) {
            #pragma unroll
            for (int kt = 0; kt < 2; ++kt) {
                f32x4 s = (f32x4){0.f, 0.f, 0.f, 0.f};
                s = __builtin_amdgcn_mfma_f32_16x16x32_bf16(kfc[kt], qf[qt], s, 0, 0, 0);
                bf16x4 pk;
                #pragma unroll
                for (int r = 0; r < 4; ++r) {
                    float p = __expf(s[r] + (float)cmv[qt][kt][r]);
                    rsum[qt] += p;
                    pk[r] = (__bf16)p;
                }
                *(bf16x4*)(&Ps[wv][l16][kt * 16 + quad * 4]) = pk;
            }
            bf16x8 pf = *(const bf16x8*)(&Ps[wv][l16][quad * 8]);
            #pragma unroll
            for (int dt = 0; dt < 2; ++dt)
                o[qt][dt] = __builtin_amdgcn_mfma_f32_16x16x32_bf16(pf, vfc[dt], o[qt][dt], 0, 0, 0);
        }
        #pragma unroll
        for (int qt = 0; qt < 4; ++qt)
            #pragma unroll
            for (int kt = 0; kt < 2; ++kt)
                cmv[qt][kt] = cmn[qt][kt];
        kfc[0] = kfn[0]; kfc[1] = kfn[1];
        vfc[0] = vfn[0]; vfc[1] = vfn[1];
    }

    #pragma unroll
    for (int qt = 0; qt < 4; ++qt) {
        float s = rsum[qt];
        s += __shfl_xor(s, 16);
        s += __shfl_xor(s, 32);
        if (quad == 0) Sums[wv][qt * 16 + l16] = 1.0f / s;
    }
    #pragma unroll
    for (int qt = 0; qt < 4; ++qt) {
        f32x4 inv = *(const f32x4*)(&Sums[wv][qt * 16 + quad * 4]);
        #pragma unroll
        for (int dt = 0; dt < 2; ++dt)
            #pragma unroll
            for (int r = 0; r < 4; ++r) {
                int qrow = q0 + qt * 16 + quad * 4 + r;
                aout[((size_t)b * NTOK + qrow) * DIMC + h * HD + dt * 16 + l16] =
                    (__bf16)(o[qt][dt][r] * inv[r]);
            }
    }
}

// ---------------- proj GEMM via MFMA (C^T orientation, float4 stores) ----------------
__launch_bounds__(256, 3)
__global__ void proj_mfma(const __bf16* __restrict__ A, const __bf16* __restrict__ Wt,
                          const float* __restrict__ bias, float* __restrict__ out) {
    __shared__ __bf16 As[256 * 64];
    __shared__ __bf16 Bs[96 * 64];
    const int t = threadIdx.x;
    const int wv = t >> 6, lane = t & 63;
    const int l16 = lane & 15, quad = lane >> 4;
    const int m0 = blockIdx.y * 256;
    const int j0 = blockIdx.x * 96;

    f32x4 acc[4][6];
    #pragma unroll
    for (int mt = 0; mt < 4; ++mt)
        #pragma unroll
        for (int nt = 0; nt < 6; ++nt)
            acc[mt][nt] = (f32x4){0.f, 0.f, 0.f, 0.f};

    for (int kit = 0; kit < 3; ++kit) {
        const int k0 = kit * 64;
        #pragma unroll
        for (int gi = 0; gi < 8; ++gi) {
            int g = wv * 8 + gi;
            int cid = g * 64 + lane;
            int row = cid >> 3, kcs = cid & 7;
            int kcg = kcs ^ (row & 7);
            gload_lds16(A + (size_t)(m0 + row) * DIMC + k0 + kcg * 8, As + g * 512);
        }
        #pragma unroll
        for (int gi = 0; gi < 3; ++gi) {
            int g = wv * 3 + gi;
            int cid = g * 64 + lane;
            int n = cid >> 3, kcs = cid & 7;
            int kcg = kcs ^ (n & 7);
            gload_lds16(Wt + (size_t)(j0 + n) * DIMC + k0 + kcg * 8, Bs + g * 512);
        }
        __syncthreads();
        #pragma unroll
        for (int kk = 0; kk < 2; ++kk) {
            bf16x8 af[4], bfr[6];
            #pragma unroll
            for (int mt = 0; mt < 4; ++mt) {
                int row = wv * 64 + mt * 16 + l16;
                int ch = (kk * 4 + quad) ^ (row & 7);
                af[mt] = *(const bf16x8*)(As + row * 64 + ch * 8);
            }
            #pragma unroll
            for (int nt = 0; nt < 6; ++nt) {
                int n = nt * 16 + l16;
                int ch = (kk * 4 + quad) ^ (n & 7);
                bfr[nt] = *(const bf16x8*)(Bs + n * 64 + ch * 8);
            }
            #pragma unroll
            for (int mt = 0; mt < 4; ++mt)
                #pragma unroll
                for (int nt = 0; nt < 6; ++nt)
                    acc[mt][nt] = __builtin_amdgcn_mfma_f32_16x16x32_bf16(bfr[nt], af[mt], acc[mt][nt], 0, 0, 0);
        }
        __syncthreads();
    }

    #pragma unroll
    for (int nt = 0; nt < 6; ++nt) {
        int colg = j0 + nt * 16 + quad * 4;
        f32x4 bv = *(const f32x4*)(bias + colg);
        #pragma unroll
        for (int mt = 0; mt < 4; ++mt) {
            int token = m0 + wv * 64 + mt * 16 + l16;
            f32x4 ov = acc[mt][nt] + bv;
            *(f32x4*)(out + (size_t)token * DIMC + colg) = ov;
        }
    }
}

extern "C" void kernel_launch(void* const* d_in, const int* in_sizes, int n_in,
                              void* d_out, int out_size, void* d_ws, size_t ws_size,
                              hipStream_t stream) {
    const float* x          = (const float*)d_in[0];
    const float* mask       = (const float*)d_in[1];
    const float* qkv_w      = (const float*)d_in[2];
    const float* qkv_b      = (const float*)d_in[3];
    const float* proj_w     = (const float*)d_in[4];
    const float* proj_b     = (const float*)d_in[5];
    const float* bias_table = (const float*)d_in[6];
    const int*   rel_index  = (const int*)d_in[7];

    char* ws = (char*)d_ws;
    __bf16* xb     = (__bf16*)(ws);                 // 25,165,824 B (reused as aoutb)
    __bf16* q      = (__bf16*)(ws + 25165824);
    __bf16* k      = (__bf16*)(ws + 50331648);
    __bf16* v      = (__bf16*)(ws + 75497472);
    __bf16* cm     = (__bf16*)(ws + 100663296);     // 50,331,648 B
    __bf16* biasTb = (__bf16*)(ws + 150994944);     //    786,432 B
    __bf16* wqt    = (__bf16*)(ws + 151781376);     //    221,184 B
    __bf16* wpt    = (__bf16*)(ws + 152002560);     //     73,728 B  (~145 MB total)
    __bf16* aoutb  = xb;

    cast_x<<<6144, 256, 0, stream>>>(x, xb);
    transcast<<<432, 256, 0, stream>>>(qkv_w, wqt, DIMC, 576);
    transcast<<<144, 256, 0, stream>>>(proj_w, wpt, DIMC, DIMC);
    biasTb_kernel<<<1536, 256, 0, stream>>>(bias_table, rel_index, biasTb);
    cm_kernel<<<dim3(384, 32), 256, 0, stream>>>(biasTb, mask, cm);
    qkv_mfma<<<dim3(6, 256), 256, 0, stream>>>(xb, wqt, qkv_b, q, k, v);
    attn_mfma<<<1536, 256, 0, stream>>>(q, k, v, cm, aoutb);
    proj_mfma<<<dim3(2, 256), 256, 0, stream>>>(aoutb, wpt, proj_b, (float*)d_out);
}

// Round 6
// 313.363 us; speedup vs baseline: 1.1069x; 1.1069x over previous
//
#include <hip/hip_runtime.h>
#include <cstdint>
#include <math.h>

#define DIMC 192
#define NTOK 256
#define HEADS 6
#define HD 32

typedef __bf16 bf16x8 __attribute__((ext_vector_type(8)));
typedef __bf16 bf16x4 __attribute__((ext_vector_type(4)));
typedef float f32x4 __attribute__((ext_vector_type(4)));

__device__ __forceinline__ void gload_lds16(const __bf16* g, __bf16* l) {
    __builtin_amdgcn_global_load_lds((const __attribute__((address_space(1))) void*)g,
                                     (__attribute__((address_space(3))) void*)l, 16, 0, 0);
}

// ---------------- cast x (fp32) -> xb (bf16) ----------------
__global__ void cast_x(const float* __restrict__ x, __bf16* __restrict__ xb) {
    int i = blockIdx.x * 256 + threadIdx.x;
    float4 a = ((const float4*)x)[i * 2];
    float4 b = ((const float4*)x)[i * 2 + 1];
    bf16x8 o = {(__bf16)a.x, (__bf16)a.y, (__bf16)a.z, (__bf16)a.w,
                (__bf16)b.x, (__bf16)b.y, (__bf16)b.z, (__bf16)b.w};
    ((bf16x8*)xb)[i] = o;
}

// ---------------- per-head gathered qkv weights: wh[h][j][k] ----------------
// j in [0,96): 0..31 = q-cols, 32..63 = k-cols, 64..95 = v-cols of head h
__global__ void wh_kernel(const float* __restrict__ w, __bf16* __restrict__ wh) {
    int i = blockIdx.x * 256 + threadIdx.x;      // < 6*96*192 = 110592
    int h = i / 18432; int r = i - h * 18432;
    int j = r / DIMC;  int k = r - j * DIMC;
    int col = (j >> 5) * DIMC + h * HD + (j & 31);
    wh[i] = (__bf16)w[(size_t)k * 576 + col];
}

// ---------------- per-head gathered qkv bias: qbh[h][j] ----------------
__global__ void qbh_kernel(const float* __restrict__ qb, float* __restrict__ qbh) {
    int i = blockIdx.x * 256 + threadIdx.x;      // < 576
    if (i >= 576) return;
    int h = i / 96; int j = i - h * 96;
    qbh[i] = qb[(j >> 5) * DIMC + h * HD + (j & 31)];
}

// ---------------- transpose+cast proj weight: wt[n][k] = w[k][n] ----------------
__global__ void transcast(const float* __restrict__ w, __bf16* __restrict__ wt, int K, int N) {
    int i = blockIdx.x * 256 + threadIdx.x;
    int n = i / K, k = i - n * K;
    wt[i] = (__bf16)w[(size_t)k * N + n];
}

// ---------------- biasTb[h][q][k] = (bf16) table[rel[q][k]*6 + h] ----------------
__global__ void biasTb_kernel(const float* __restrict__ table, const int* __restrict__ rel,
                              __bf16* __restrict__ biasTb) {
    int i = blockIdx.x * 256 + threadIdx.x;
    int h = i >> 16;
    int r = i & 65535;
    biasTb[i] = (__bf16)table[rel[r] * 6 + h];
}

// ---------------- maskb = (bf16) mask ----------------
__global__ void maskb_kernel(const float* __restrict__ m, __bf16* __restrict__ mb) {
    int i = blockIdx.x * 256 + threadIdx.x;
    float4 a = ((const float4*)m)[i * 2];
    float4 b = ((const float4*)m)[i * 2 + 1];
    bf16x8 o = {(__bf16)a.x, (__bf16)a.y, (__bf16)a.z, (__bf16)a.w,
                (__bf16)b.x, (__bf16)b.y, (__bf16)b.z, (__bf16)b.w};
    ((bf16x8*)mb)[i] = o;
}

// ---------------- fused per-(b,h) QKV-GEMM + attention ----------------
// Phase 1: x[b](256x192) @ wh[h](192x96) via MFMA (C^T), accs -> LDS K/VT/Q.
// Phase 2: S^T-orientation attention (round-4 structure), bf16 bias+mask.
// Grid map keeps all blocks sharing mask[w] / x[b] on one XCD (xcd = g & 7).
__launch_bounds__(256, 2)
__global__ void fused_qkv_attn(const __bf16* __restrict__ xb, const __bf16* __restrict__ wh,
                               const float* __restrict__ qbh, const __bf16* __restrict__ biasTb,
                               const __bf16* __restrict__ maskb, __bf16* __restrict__ aout) {
    __shared__ __align__(16) __bf16 smem[29952];   // 59904 B -> 2 blocks/CU
    __bf16* xs   = smem;                  // [256][32] (phase 1)
    __bf16* Wsm  = smem + 8192;           // [96][32]  (phase 1)
    __bf16* Qs   = smem;                  // [256][40] (phase 2 start, after barrier)
    __bf16* Ps   = smem;                  // [4][16][40] (chunk loop, after barrier)
    float*  Sums = (float*)(smem + 5120); // [4][64]
    __bf16* Ks   = smem + 11264;          // [256][40]
    __bf16* VTs  = smem + 21504;          // [32][264]

    const int g = blockIdx.x;
    const int xcd = g & 7;
    const int slot = g >> 3;              // [0,192)
    const int wgrp = slot / 24;
    const int inner = slot - wgrp * 24;
    const int w = wgrp * 8 + xcd;
    const int h = inner >> 2;
    const int rep = inner & 3;
    const int b = rep * 64 + w;

    const int t = threadIdx.x;
    const int wv = t >> 6, lane = t & 63;
    const int l16 = lane & 15, quad = lane >> 4;
    const int q0 = wv * 64;

    // ---- Phase 1: per-head QKV GEMM ----
    f32x4 acc[4][6];
    #pragma unroll
    for (int mt = 0; mt < 4; ++mt)
        #pragma unroll
        for (int nt = 0; nt < 6; ++nt)
            acc[mt][nt] = (f32x4){0.f, 0.f, 0.f, 0.f};

    const __bf16* xbb = xb + (size_t)b * (NTOK * DIMC);
    const __bf16* whh = wh + h * (96 * DIMC);
    for (int kit = 0; kit < 6; ++kit) {
        const int k0 = kit * 32;
        for (int gg = wv; gg < 22; gg += 4) {      // wave-uniform
            if (gg < 16) {                          // x tile: 1024 chunks
                int cid = gg * 64 + lane;
                int row = cid >> 2, kcs = cid & 3;
                int kcg = kcs ^ (row & 3);
                gload_lds16(xbb + row * DIMC + k0 + kcg * 8, xs + cid * 8);
            } else {                                // W tile: 384 chunks
                int cid = (gg - 16) * 64 + lane;
                int j = cid >> 2, kcs = cid & 3;
                int kcg = kcs ^ (j & 3);
                gload_lds16(whh + j * DIMC + k0 + kcg * 8, Wsm + cid * 8);
            }
        }
        __syncthreads();
        const int ch = (quad ^ (l16 & 3)) * 8;
        bf16x8 af[4], bfr[6];
        #pragma unroll
        for (int mt = 0; mt < 4; ++mt)
            af[mt] = *(const bf16x8*)(xs + (wv * 64 + mt * 16 + l16) * 32 + ch);
        #pragma unroll
        for (int nt = 0; nt < 6; ++nt)
            bfr[nt] = *(const bf16x8*)(Wsm + (nt * 16 + l16) * 32 + ch);
        #pragma unroll
        for (int mt = 0; mt < 4; ++mt)
            #pragma unroll
            for (int nt = 0; nt < 6; ++nt)          // C^T: row = j (qkv col), col = token
                acc[mt][nt] = __builtin_amdgcn_mfma_f32_16x16x32_bf16(bfr[nt], af[mt], acc[mt][nt], 0, 0, 0);
        __syncthreads();
    }

    // ---- Phase 1 epilogue: accs -> LDS Q/K/VT (wave-local tokens) ----
    f32x4 qb[6];
    #pragma unroll
    for (int nt = 0; nt < 6; ++nt)
        qb[nt] = *(const f32x4*)(qbh + h * 96 + nt * 16 + quad * 4);
    const float qscale = 0.17677669529663687f;      // 1/sqrt(32)
    #pragma unroll
    for (int mt = 0; mt < 4; ++mt) {
        int tok = wv * 64 + mt * 16 + l16;
        #pragma unroll
        for (int nt = 0; nt < 6; ++nt) {
            int j0 = nt * 16 + quad * 4;
            f32x4 vals;
            #pragma unroll
            for (int r = 0; r < 4; ++r) vals[r] = acc[mt][nt][r] + qb[nt][r];
            if (nt < 2) {
                bf16x4 qv;
                #pragma unroll
                for (int r = 0; r < 4; ++r) qv[r] = (__bf16)(vals[r] * qscale);
                *(bf16x4*)(Qs + tok * 40 + j0) = qv;
            } else if (nt < 4) {
                bf16x4 kv;
                #pragma unroll
                for (int r = 0; r < 4; ++r) kv[r] = (__bf16)vals[r];
                *(bf16x4*)(Ks + tok * 40 + (j0 - 32)) = kv;
            } else {
                #pragma unroll
                for (int r = 0; r < 4; ++r)
                    VTs[(j0 - 64 + r) * 264 + tok] = (__bf16)vals[r];
            }
        }
    }
    __syncthreads();

    // Q fragments, then barrier before Ps overlays Qs
    bf16x8 qf[4];
    #pragma unroll
    for (int qt = 0; qt < 4; ++qt)
        qf[qt] = *(const bf16x8*)(Qs + (q0 + qt * 16 + l16) * 40 + quad * 8);
    __syncthreads();

    // ---- Phase 2: attention (S^T orientation) ----
    f32x4 o[4][2];
    #pragma unroll
    for (int qt = 0; qt < 4; ++qt)
        #pragma unroll
        for (int dt = 0; dt < 2; ++dt)
            o[qt][dt] = (f32x4){0.f, 0.f, 0.f, 0.f};
    float rsum[4] = {};

    const __bf16* bb = biasTb + (size_t)h * 65536 + (size_t)(q0 + l16) * 256 + quad * 4;
    const __bf16* mb = maskb + (size_t)w * 65536 + (size_t)(q0 + l16) * 256 + quad * 4;

    bf16x4 bqv[4][2], mqv[4][2];
    bf16x8 kfc[2], vfc[2];
    #pragma unroll
    for (int qt = 0; qt < 4; ++qt)
        #pragma unroll
        for (int kt = 0; kt < 2; ++kt) {
            bqv[qt][kt] = *(const bf16x4*)(bb + qt * 4096 + kt * 16);
            mqv[qt][kt] = *(const bf16x4*)(mb + qt * 4096 + kt * 16);
        }
    #pragma unroll
    for (int kt = 0; kt < 2; ++kt)
        kfc[kt] = *(const bf16x8*)(Ks + (kt * 16 + l16) * 40 + quad * 8);
    #pragma unroll
    for (int dt = 0; dt < 2; ++dt)
        vfc[dt] = *(const bf16x8*)(VTs + (dt * 16 + l16) * 264 + quad * 8);

    #pragma unroll
    for (int c = 0; c < 8; ++c) {
        const int kbn = ((c + 1) & 7) * 32;         // next chunk (wraps; unused at c=7)
        bf16x4 bqn[4][2], mqn[4][2];
        bf16x8 kfn[2], vfn[2];
        #pragma unroll
        for (int qt = 0; qt < 4; ++qt)
            #pragma unroll
            for (int kt = 0; kt < 2; ++kt) {
                bqn[qt][kt] = *(const bf16x4*)(bb + qt * 4096 + kbn + kt * 16);
                mqn[qt][kt] = *(const bf16x4*)(mb + qt * 4096 + kbn + kt * 16);
            }
        #pragma unroll
        for (int kt = 0; kt < 2; ++kt)
            kfn[kt] = *(const bf16x8*)(Ks + (kbn + kt * 16 + l16) * 40 + quad * 8);
        #pragma unroll
        for (int dt = 0; dt < 2; ++dt)
            vfn[dt] = *(const bf16x8*)(VTs + (dt * 16 + l16) * 264 + kbn + quad * 8);

        #pragma unroll
        for (int qt = 0; qt < 4; ++qt) {
            #pragma unroll
            for (int kt = 0; kt < 2; ++kt) {
                f32x4 s = (f32x4){0.f, 0.f, 0.f, 0.f};
                s = __builtin_amdgcn_mfma_f32_16x16x32_bf16(kfc[kt], qf[qt], s, 0, 0, 0);
                bf16x4 pk;
                #pragma unroll
                for (int r = 0; r < 4; ++r) {
                    float p = __expf(s[r] + (float)bqv[qt][kt][r] + (float)mqv[qt][kt][r]);
                    rsum[qt] += p;
                    pk[r] = (__bf16)p;
                }
                *(bf16x4*)(Ps + (wv * 16 + l16) * 40 + kt * 16 + quad * 4) = pk;
            }
            bf16x8 pf = *(const bf16x8*)(Ps + (wv * 16 + l16) * 40 + quad * 8);
            #pragma unroll
            for (int dt = 0; dt < 2; ++dt)
                o[qt][dt] = __builtin_amdgcn_mfma_f32_16x16x32_bf16(pf, vfc[dt], o[qt][dt], 0, 0, 0);
        }
        #pragma unroll
        for (int qt = 0; qt < 4; ++qt)
            #pragma unroll
            for (int kt = 0; kt < 2; ++kt) {
                bqv[qt][kt] = bqn[qt][kt];
                mqv[qt][kt] = mqn[qt][kt];
            }
        kfc[0] = kfn[0]; kfc[1] = kfn[1];
        vfc[0] = vfn[0]; vfc[1] = vfn[1];
    }

    #pragma unroll
    for (int qt = 0; qt < 4; ++qt) {
        float s = rsum[qt];
        s += __shfl_xor(s, 16);
        s += __shfl_xor(s, 32);
        if (quad == 0) Sums[wv * 64 + qt * 16 + l16] = 1.0f / s;
    }
    #pragma unroll
    for (int qt = 0; qt < 4; ++qt) {
        f32x4 inv = *(const f32x4*)(Sums + wv * 64 + qt * 16 + quad * 4);
        #pragma unroll
        for (int dt = 0; dt < 2; ++dt)
            #pragma unroll
            for (int r = 0; r < 4; ++r) {
                int qrow = q0 + qt * 16 + quad * 4 + r;
                aout[((size_t)b * NTOK + qrow) * DIMC + h * HD + dt * 16 + l16] =
                    (__bf16)(o[qt][dt][r] * inv[r]);
            }
    }
}

// ---------------- proj GEMM via MFMA (C^T, float4 stores), XCD-aware grid ----------------
__launch_bounds__(256, 3)
__global__ void proj_mfma(const __bf16* __restrict__ A, const __bf16* __restrict__ Wt,
                          const float* __restrict__ bias, float* __restrict__ out) {
    __shared__ __bf16 As[256 * 64];
    __shared__ __bf16 Bs[96 * 64];
    const int t = threadIdx.x;
    const int wv = t >> 6, lane = t & 63;
    const int l16 = lane & 15, quad = lane >> 4;
    const int g = blockIdx.x;                 // both bx of one by land on one XCD
    const int xcd = g & 7, slot = g >> 3;
    const int bx = slot & 1;
    const int by = (slot >> 1) * 8 + xcd;
    const int m0 = by * 256;
    const int j0 = bx * 96;

    f32x4 acc[4][6];
    #pragma unroll
    for (int mt = 0; mt < 4; ++mt)
        #pragma unroll
        for (int nt = 0; nt < 6; ++nt)
            acc[mt][nt] = (f32x4){0.f, 0.f, 0.f, 0.f};

    for (int kit = 0; kit < 3; ++kit) {
        const int k0 = kit * 64;
        #pragma unroll
        for (int gi = 0; gi < 8; ++gi) {
            int gg = wv * 8 + gi;
            int cid = gg * 64 + lane;
            int row = cid >> 3, kcs = cid & 7;
            int kcg = kcs ^ (row & 7);
            gload_lds16(A + (size_t)(m0 + row) * DIMC + k0 + kcg * 8, As + gg * 512);
        }
        #pragma unroll
        for (int gi = 0; gi < 3; ++gi) {
            int gg = wv * 3 + gi;
            int cid = gg * 64 + lane;
            int n = cid >> 3, kcs = cid & 7;
            int kcg = kcs ^ (n & 7);
            gload_lds16(Wt + (size_t)(j0 + n) * DIMC + k0 + kcg * 8, Bs + gg * 512);
        }
        __syncthreads();
        #pragma unroll
        for (int kk = 0; kk < 2; ++kk) {
            bf16x8 af[4], bfr[6];
            #pragma unroll
            for (int mt = 0; mt < 4; ++mt) {
                int row = wv * 64 + mt * 16 + l16;
                int ch = (kk * 4 + quad) ^ (row & 7);
                af[mt] = *(const bf16x8*)(As + row * 64 + ch * 8);
            }
            #pragma unroll
            for (int nt = 0; nt < 6; ++nt) {
                int n = nt * 16 + l16;
                int ch = (kk * 4 + quad) ^ (n & 7);
                bfr[nt] = *(const bf16x8*)(Bs + n * 64 + ch * 8);
            }
            #pragma unroll
            for (int mt = 0; mt < 4; ++mt)
                #pragma unroll
                for (int nt = 0; nt < 6; ++nt)
                    acc[mt][nt] = __builtin_amdgcn_mfma_f32_16x16x32_bf16(bfr[nt], af[mt], acc[mt][nt], 0, 0, 0);
        }
        __syncthreads();
    }

    #pragma unroll
    for (int nt = 0; nt < 6; ++nt) {
        int colg = j0 + nt * 16 + quad * 4;
        f32x4 bv = *(const f32x4*)(bias + colg);
        #pragma unroll
        for (int mt = 0; mt < 4; ++mt) {
            int token = m0 + wv * 64 + mt * 16 + l16;
            f32x4 ov = acc[mt][nt] + bv;
            *(f32x4*)(out + (size_t)token * DIMC + colg) = ov;
        }
    }
}

extern "C" void kernel_launch(void* const* d_in, const int* in_sizes, int n_in,
                              void* d_out, int out_size, void* d_ws, size_t ws_size,
                              hipStream_t stream) {
    const float* x          = (const float*)d_in[0];
    const float* mask       = (const float*)d_in[1];
    const float* qkv_w      = (const float*)d_in[2];
    const float* qkv_b      = (const float*)d_in[3];
    const float* proj_w     = (const float*)d_in[4];
    const float* proj_b     = (const float*)d_in[5];
    const float* bias_table = (const float*)d_in[6];
    const int*   rel_index  = (const int*)d_in[7];

    char* ws = (char*)d_ws;
    __bf16* xb     = (__bf16*)(ws);                 // 25,165,824 B
    __bf16* aoutb  = (__bf16*)(ws + 25165824);      // 25,165,824 B
    __bf16* biasTb = (__bf16*)(ws + 50331648);      //    786,432 B
    __bf16* maskb  = (__bf16*)(ws + 51118080);      //  8,388,608 B
    __bf16* wh     = (__bf16*)(ws + 59506688);      //    221,184 B
    float*  qbh    = (float*)(ws + 59727872);       //      2,304 B
    __bf16* wpt    = (__bf16*)(ws + 59730176);      //     73,728 B  (~59.8 MB total)

    cast_x<<<6144, 256, 0, stream>>>(x, xb);
    wh_kernel<<<432, 256, 0, stream>>>(qkv_w, wh);
    qbh_kernel<<<3, 256, 0, stream>>>(qkv_b, qbh);
    transcast<<<144, 256, 0, stream>>>(proj_w, wpt, DIMC, DIMC);
    biasTb_kernel<<<1536, 256, 0, stream>>>(bias_table, rel_index, biasTb);
    maskb_kernel<<<2048, 256, 0, stream>>>(mask, maskb);
    fused_qkv_attn<<<1536, 256, 0, stream>>>(xb, wh, qbh, biasTb, maskb, aoutb);
    proj_mfma<<<512, 256, 0, stream>>>(aoutb, wpt, proj_b, (float*)d_out);
}